// Round 1
// baseline (22.874 us; speedup 1.0000x reference)
//
#include <hip/hip_runtime.h>
#include <hip/hip_bf16.h>

// Shapes (fixed by the reference)
constexpr int IN_F  = 1024;
constexpr int OUT_F = 1024;
constexpr int LAT   = 16;
constexpr int BATCH = 256;

typedef __attribute__((ext_vector_type(8))) short  bf16x8;  // 8 bf16 (4 VGPRs)
typedef __attribute__((ext_vector_type(4))) float  f32x4;   // MFMA accumulator

// ---------------------------------------------------------------------------
// Kernel 1: s = z @ lt_w^T + lt_b ; xs = bf16(tensor * s); ss = bf16(s*s)
// grid = BATCH blocks (one per row), 256 threads
// ---------------------------------------------------------------------------
__global__ __launch_bounds__(256) void prep_s(
    const float* __restrict__ tensor, const float* __restrict__ z,
    const float* __restrict__ lt_w, const float* __restrict__ lt_b,
    __hip_bfloat16* __restrict__ xs, __hip_bfloat16* __restrict__ ss) {
  const int b = blockIdx.x;
  // broadcast-load z row (16 floats) into registers
  float zr[LAT];
  const float4* z4 = reinterpret_cast<const float4*>(z + b * LAT);
#pragma unroll
  for (int j = 0; j < LAT / 4; ++j) {
    float4 v = z4[j];
    zr[4 * j + 0] = v.x; zr[4 * j + 1] = v.y;
    zr[4 * j + 2] = v.z; zr[4 * j + 3] = v.w;
  }
#pragma unroll
  for (int it = 0; it < IN_F / 256; ++it) {
    const int i = it * 256 + threadIdx.x;
    const float4* lw = reinterpret_cast<const float4*>(lt_w + i * LAT);
    float s = lt_b[i];
#pragma unroll
    for (int j = 0; j < LAT / 4; ++j) {
      float4 v = lw[j];
      s += zr[4 * j + 0] * v.x + zr[4 * j + 1] * v.y +
           zr[4 * j + 2] * v.z + zr[4 * j + 3] * v.w;
    }
    const float x = tensor[b * IN_F + i];
    xs[b * IN_F + i] = __float2bfloat16(x * s);
    ss[b * IN_F + i] = __float2bfloat16(s * s);
  }
}

// ---------------------------------------------------------------------------
// Kernel 2: wt[n][k] = bf16(W[k][n]); w2t[n][k] = bf16(W[k][n]^2)
// 32x32 tile transpose via padded LDS. grid = (32, 32), 256 threads.
// ---------------------------------------------------------------------------
__global__ __launch_bounds__(256) void prep_w(
    const float* __restrict__ W,
    __hip_bfloat16* __restrict__ wt, __hip_bfloat16* __restrict__ w2t) {
  __shared__ float tile[32][33];
  const int n0 = blockIdx.x * 32;
  const int k0 = blockIdx.y * 32;
  const int tx = threadIdx.x & 31;       // n-local on load, k-local on store
  const int ty = threadIdx.x >> 5;       // 0..7
#pragma unroll
  for (int i = 0; i < 4; ++i) {
    const int k = ty + i * 8;
    tile[k][tx] = W[(k0 + k) * OUT_F + n0 + tx];   // coalesced 128B rows
  }
  __syncthreads();
#pragma unroll
  for (int i = 0; i < 4; ++i) {
    const int n = ty + i * 8;
    const float v = tile[tx][n];                   // stride-33: conflict-free
    wt [(n0 + n) * IN_F + k0 + tx] = __float2bfloat16(v);
    w2t[(n0 + n) * IN_F + k0 + tx] = __float2bfloat16(v * v);
  }
}

// ---------------------------------------------------------------------------
// Kernel 3: fused double-GEMM + demodulation epilogue
//   acc1 = xs @ W  (via wt),  acc2 = ss @ W^2 (via w2t)
//   out  = acc1 * rsqrt(acc2 + 1e-8) + bias
// BM=BN=32, BK=64; 256 threads = 4 waves in 2x2, each owning a 16x16 tile.
// grid = (N/32, M/32) = (32, 8) = 256 blocks.
// LDS tiles are [32 rows][64 bf16] with 16B-chunk XOR swizzle (chunk ^= row&7).
// ---------------------------------------------------------------------------
__global__ __launch_bounds__(256) void gemm_mod(
    const __hip_bfloat16* __restrict__ xs, const __hip_bfloat16* __restrict__ ss,
    const __hip_bfloat16* __restrict__ wt, const __hip_bfloat16* __restrict__ w2t,
    const float* __restrict__ bias, float* __restrict__ out) {
  __shared__ __hip_bfloat16 lds[4][32 * 64];  // xs, ss, wt, w2t tiles (4KB each)

  const int n0 = blockIdx.x * 32;
  const int m0 = blockIdx.y * 32;
  const int t = threadIdx.x;
  const int lane = t & 63;
  const int wave = t >> 6;
  const int wm = wave >> 1;   // 0..1
  const int wn = wave & 1;    // 0..1

  // staging map: thread t -> (row = t>>3, 16B chunk c = t&7) of each tile
  const int srow = t >> 3;
  const int sc = t & 7;
  const int swz_off = srow * 128 + ((sc ^ (srow & 7)) << 4);  // LDS byte offset
  const int gofs_a = (m0 + srow) * IN_F + sc * 8;             // bf16 elements
  const int gofs_b = (n0 + srow) * IN_F + sc * 8;

  // fragment addressing: lane holds row (l&15), k-halfgroup h = l>>4 (8 bf16)
  const int frow = lane & 15;
  const int h = lane >> 4;          // 0..3
  const int arow = wm * 16 + frow;  // row within A tiles
  const int brow = wn * 16 + frow;  // row (= n-local) within B tiles

  f32x4 acc1 = {0.f, 0.f, 0.f, 0.f};
  f32x4 acc2 = {0.f, 0.f, 0.f, 0.f};

  char* l0 = reinterpret_cast<char*>(lds[0]);
  char* l1 = reinterpret_cast<char*>(lds[1]);
  char* l2 = reinterpret_cast<char*>(lds[2]);
  char* l3 = reinterpret_cast<char*>(lds[3]);

  for (int k0 = 0; k0 < IN_F; k0 += 64) {
    __syncthreads();  // protect previous iteration's reads
    // issue all 4 global loads first, then LDS writes
    bf16x8 va = *reinterpret_cast<const bf16x8*>(xs  + gofs_a + k0);
    bf16x8 vb = *reinterpret_cast<const bf16x8*>(ss  + gofs_a + k0);
    bf16x8 vc = *reinterpret_cast<const bf16x8*>(wt  + gofs_b + k0);
    bf16x8 vd = *reinterpret_cast<const bf16x8*>(w2t + gofs_b + k0);
    *reinterpret_cast<bf16x8*>(l0 + swz_off) = va;
    *reinterpret_cast<bf16x8*>(l1 + swz_off) = vb;
    *reinterpret_cast<bf16x8*>(l2 + swz_off) = vc;
    *reinterpret_cast<bf16x8*>(l3 + swz_off) = vd;
    __syncthreads();

#pragma unroll
    for (int s = 0; s < 2; ++s) {  // two K=32 sub-steps per BK=64
      const int ca = s * 4 + h;    // 16B chunk index holding this lane's 8 k's
      const int aoff = arow * 128 + ((ca ^ (arow & 7)) << 4);
      const int boff = brow * 128 + ((ca ^ (brow & 7)) << 4);
      bf16x8 a1 = *reinterpret_cast<const bf16x8*>(l0 + aoff);
      bf16x8 a2 = *reinterpret_cast<const bf16x8*>(l1 + aoff);
      bf16x8 b1 = *reinterpret_cast<const bf16x8*>(l2 + boff);
      bf16x8 b2 = *reinterpret_cast<const bf16x8*>(l3 + boff);
      acc1 = __builtin_amdgcn_mfma_f32_16x16x32_bf16(a1, b1, acc1, 0, 0, 0);
      acc2 = __builtin_amdgcn_mfma_f32_16x16x32_bf16(a2, b2, acc2, 0, 0, 0);
    }
  }

  // epilogue: C/D layout is col = lane&15, row = (lane>>4)*4 + reg
  const int col = n0 + wn * 16 + (lane & 15);
  const float bs = bias[col];
#pragma unroll
  for (int q = 0; q < 4; ++q) {
    const int row = m0 + wm * 16 + (lane >> 4) * 4 + q;
    out[row * OUT_F + col] = acc1[q] * __frsqrt_rn(acc2[q] + 1e-8f) + bs;
  }
}

// ---------------------------------------------------------------------------
extern "C" void kernel_launch(void* const* d_in, const int* in_sizes, int n_in,
                              void* d_out, int out_size, void* d_ws, size_t ws_size,
                              hipStream_t stream) {
  const float* tensor = (const float*)d_in[0];  // [256][1024]
  const float* z      = (const float*)d_in[1];  // [256][16]
  const float* W      = (const float*)d_in[2];  // [1024][1024]
  const float* bias   = (const float*)d_in[3];  // [1024]
  const float* lt_w   = (const float*)d_in[4];  // [1024][16]
  const float* lt_b   = (const float*)d_in[5];  // [1024]
  float* out = (float*)d_out;

  // workspace layout (needs 5 MB):
  //   [0, 512K)   xs   bf16 [256][1024]
  //   [512K, 1M)  ss   bf16 [256][1024]
  //   [1M, 3M)    wt   bf16 [1024][1024]  (W transposed)
  //   [3M, 5M)    w2t  bf16 [1024][1024]  (W^2 transposed)
  char* ws = (char*)d_ws;
  __hip_bfloat16* xs  = (__hip_bfloat16*)(ws);
  __hip_bfloat16* ssb = (__hip_bfloat16*)(ws + 512 * 1024);
  __hip_bfloat16* wt  = (__hip_bfloat16*)(ws + 1024 * 1024);
  __hip_bfloat16* w2t = (__hip_bfloat16*)(ws + 3 * 1024 * 1024);

  prep_s<<<BATCH, 256, 0, stream>>>(tensor, z, lt_w, lt_b, xs, ssb);
  prep_w<<<dim3(OUT_F / 32, IN_F / 32), 256, 0, stream>>>(W, wt, w2t);
  gemm_mod<<<dim3(OUT_F / 32, BATCH / 32), 256, 0, stream>>>(xs, ssb, wt, w2t, bias, out);
}

// Round 2
// 19.422 us; speedup vs baseline: 1.1777x; 1.1777x over previous
//
#include <hip/hip_runtime.h>
#include <hip/hip_bf16.h>

// Shapes (fixed by the reference)
constexpr int IN_F  = 1024;
constexpr int OUT_F = 1024;
constexpr int LAT   = 16;
constexpr int BATCH = 256;

typedef __attribute__((ext_vector_type(8))) short  bf16x8;  // 8 bf16 (4 VGPRs)
typedef __attribute__((ext_vector_type(4))) float  f32x4;   // MFMA accumulator

static __device__ __forceinline__ unsigned short bf16_bits(float v) {
  __hip_bfloat16 h = __float2bfloat16(v);
  return *reinterpret_cast<unsigned short*>(&h);
}

// ---------------------------------------------------------------------------
// Kernel 1 (fused prep):
//   blocks [0,1024):  wt[n][k] = bf16(W[k][n]); w2t[n][k] = bf16(W[k][n]^2)
//   blocks [1024,1280): s = z @ lt_w^T + lt_b; xs = bf16(x*s); ss = bf16(s*s)
// ---------------------------------------------------------------------------
__global__ __launch_bounds__(256) void prep(
    const float* __restrict__ tensor, const float* __restrict__ z,
    const float* __restrict__ lt_w, const float* __restrict__ lt_b,
    const float* __restrict__ W,
    __hip_bfloat16* __restrict__ xs, __hip_bfloat16* __restrict__ ss,
    __hip_bfloat16* __restrict__ wt, __hip_bfloat16* __restrict__ w2t) {
  __shared__ float tile[32][33];
  const int t = threadIdx.x;
  if (blockIdx.x < 1024) {
    // ---- W transpose + bf16 convert (+ squared copy) ----
    const int n0 = (blockIdx.x & 31) * 32;
    const int k0 = (blockIdx.x >> 5) * 32;
    const int tx = t & 31;
    const int ty = t >> 5;  // 0..7
#pragma unroll
    for (int i = 0; i < 4; ++i) {
      const int k = ty + i * 8;
      tile[k][tx] = W[(k0 + k) * OUT_F + n0 + tx];  // coalesced 128B rows
    }
    __syncthreads();
    // store side: thread -> (n = t>>3, kq = t&7), 4 k-consecutive bf16 (8B)
    const int n = t >> 3;
    const int kq = t & 7;
    union { unsigned short u[4]; uint2 v; } p1, p2;
#pragma unroll
    for (int i = 0; i < 4; ++i) {
      const float v = tile[4 * kq + i][n];  // stride-33: conflict-light
      p1.u[i] = bf16_bits(v);
      p2.u[i] = bf16_bits(v * v);
    }
    const int eofs = (n0 + n) * IN_F + k0 + 4 * kq;  // multiple of 4 -> 8B aligned
    *reinterpret_cast<uint2*>(wt + eofs)  = p1.v;
    *reinterpret_cast<uint2*>(w2t + eofs) = p2.v;
  } else {
    // ---- s / xs / ss ----
    const int b = blockIdx.x - 1024;
    float zr[LAT];
    const float4* z4 = reinterpret_cast<const float4*>(z + b * LAT);
#pragma unroll
    for (int j = 0; j < LAT / 4; ++j) {
      float4 v = z4[j];
      zr[4 * j + 0] = v.x; zr[4 * j + 1] = v.y;
      zr[4 * j + 2] = v.z; zr[4 * j + 3] = v.w;
    }
    const int i0 = t * 4;  // 256 threads x 4 elements = 1024
    float s[4];
#pragma unroll
    for (int j = 0; j < 4; ++j) {
      const float4* lw = reinterpret_cast<const float4*>(lt_w + (i0 + j) * LAT);
      float acc = lt_b[i0 + j];
#pragma unroll
      for (int q = 0; q < LAT / 4; ++q) {
        float4 v = lw[q];
        acc += zr[4 * q + 0] * v.x + zr[4 * q + 1] * v.y +
               zr[4 * q + 2] * v.z + zr[4 * q + 3] * v.w;
      }
      s[j] = acc;
    }
    const float4 x = *reinterpret_cast<const float4*>(tensor + b * IN_F + i0);
    union { unsigned short u[4]; uint2 v; } pxs, pss;
    pxs.u[0] = bf16_bits(x.x * s[0]); pss.u[0] = bf16_bits(s[0] * s[0]);
    pxs.u[1] = bf16_bits(x.y * s[1]); pss.u[1] = bf16_bits(s[1] * s[1]);
    pxs.u[2] = bf16_bits(x.z * s[2]); pss.u[2] = bf16_bits(s[2] * s[2]);
    pxs.u[3] = bf16_bits(x.w * s[3]); pss.u[3] = bf16_bits(s[3] * s[3]);
    *reinterpret_cast<uint2*>(xs + b * IN_F + i0) = pxs.v;
    *reinterpret_cast<uint2*>(ss + b * IN_F + i0) = pss.v;
  }
}

// ---------------------------------------------------------------------------
// Kernel 2: fused double-GEMM + demodulation epilogue, double-buffered LDS.
//   acc1 = xs @ W (via wt), acc2 = ss @ W^2 (via w2t)
//   out  = acc1 * rsqrt(acc2 + 1e-8) + bias
// BM=BN=32, BK=64; 256 threads = 4 waves (2x2 of 16x16). grid (32, 8).
// One __syncthreads per K-iter; next tile's global loads issued before MFMA.
// ---------------------------------------------------------------------------
__global__ __launch_bounds__(256) void gemm_mod(
    const __hip_bfloat16* __restrict__ xs, const __hip_bfloat16* __restrict__ ss,
    const __hip_bfloat16* __restrict__ wt, const __hip_bfloat16* __restrict__ w2t,
    const float* __restrict__ bias, float* __restrict__ out) {
  __shared__ __hip_bfloat16 lds[2][4][32 * 64];  // [buf][xs,ss,wt,w2t][tile]

  const int n0 = blockIdx.x * 32;
  const int m0 = blockIdx.y * 32;
  const int t = threadIdx.x;
  const int lane = t & 63;
  const int wave = t >> 6;
  const int wm = wave >> 1;
  const int wn = wave & 1;

  // staging map: thread t -> (row = t>>3, 16B chunk c = t&7)
  const int srow = t >> 3;
  const int sc = t & 7;
  const int swz_off = srow * 128 + ((sc ^ (srow & 7)) << 4);  // LDS byte offset
  const int gofs_a = (m0 + srow) * IN_F + sc * 8;
  const int gofs_b = (n0 + srow) * IN_F + sc * 8;

  // fragment addressing
  const int frow = lane & 15;
  const int h = lane >> 4;  // 0..3
  const int arow = wm * 16 + frow;
  const int brow = wn * 16 + frow;
  const int aoff0 = arow * 128 + (((0 + h) ^ (arow & 7)) << 4);
  const int aoff1 = arow * 128 + (((4 + h) ^ (arow & 7)) << 4);
  const int boff0 = brow * 128 + (((0 + h) ^ (brow & 7)) << 4);
  const int boff1 = brow * 128 + (((4 + h) ^ (brow & 7)) << 4);

  f32x4 acc1 = {0.f, 0.f, 0.f, 0.f};
  f32x4 acc2 = {0.f, 0.f, 0.f, 0.f};

  // prologue: load K-tile 0 into regs
  bf16x8 ra = *reinterpret_cast<const bf16x8*>(xs  + gofs_a);
  bf16x8 rb = *reinterpret_cast<const bf16x8*>(ss  + gofs_a);
  bf16x8 rc = *reinterpret_cast<const bf16x8*>(wt  + gofs_b);
  bf16x8 rd = *reinterpret_cast<const bf16x8*>(w2t + gofs_b);

#pragma unroll
  for (int tstep = 0; tstep < IN_F / 64; ++tstep) {
    char* l0 = reinterpret_cast<char*>(lds[tstep & 1][0]);
    char* l1 = reinterpret_cast<char*>(lds[tstep & 1][1]);
    char* l2 = reinterpret_cast<char*>(lds[tstep & 1][2]);
    char* l3 = reinterpret_cast<char*>(lds[tstep & 1][3]);
    // write staged regs (compiler inserts vmcnt wait here)
    *reinterpret_cast<bf16x8*>(l0 + swz_off) = ra;
    *reinterpret_cast<bf16x8*>(l1 + swz_off) = rb;
    *reinterpret_cast<bf16x8*>(l2 + swz_off) = rc;
    *reinterpret_cast<bf16x8*>(l3 + swz_off) = rd;
    __syncthreads();
    // issue next tile's global loads (hidden under ds_read + MFMA below)
    if (tstep < IN_F / 64 - 1) {
      const int k0 = (tstep + 1) * 64;
      ra = *reinterpret_cast<const bf16x8*>(xs  + gofs_a + k0);
      rb = *reinterpret_cast<const bf16x8*>(ss  + gofs_a + k0);
      rc = *reinterpret_cast<const bf16x8*>(wt  + gofs_b + k0);
      rd = *reinterpret_cast<const bf16x8*>(w2t + gofs_b + k0);
    }
    // MFMA on current buffer (two K=32 sub-steps)
    bf16x8 a1 = *reinterpret_cast<const bf16x8*>(l0 + aoff0);
    bf16x8 a2 = *reinterpret_cast<const bf16x8*>(l1 + aoff0);
    bf16x8 b1 = *reinterpret_cast<const bf16x8*>(l2 + boff0);
    bf16x8 b2 = *reinterpret_cast<const bf16x8*>(l3 + boff0);
    acc1 = __builtin_amdgcn_mfma_f32_16x16x32_bf16(a1, b1, acc1, 0, 0, 0);
    acc2 = __builtin_amdgcn_mfma_f32_16x16x32_bf16(a2, b2, acc2, 0, 0, 0);
    a1 = *reinterpret_cast<const bf16x8*>(l0 + aoff1);
    a2 = *reinterpret_cast<const bf16x8*>(l1 + aoff1);
    b1 = *reinterpret_cast<const bf16x8*>(l2 + boff1);
    b2 = *reinterpret_cast<const bf16x8*>(l3 + boff1);
    acc1 = __builtin_amdgcn_mfma_f32_16x16x32_bf16(a1, b1, acc1, 0, 0, 0);
    acc2 = __builtin_amdgcn_mfma_f32_16x16x32_bf16(a2, b2, acc2, 0, 0, 0);
  }

  // epilogue: C/D layout is col = lane&15, row = (lane>>4)*4 + reg
  const int col = n0 + wn * 16 + (lane & 15);
  const float bs = bias[col];
#pragma unroll
  for (int q = 0; q < 4; ++q) {
    const int row = m0 + wm * 16 + (lane >> 4) * 4 + q;
    out[row * OUT_F + col] = acc1[q] * __frsqrt_rn(acc2[q] + 1e-8f) + bs;
  }
}

// ---------------------------------------------------------------------------
extern "C" void kernel_launch(void* const* d_in, const int* in_sizes, int n_in,
                              void* d_out, int out_size, void* d_ws, size_t ws_size,
                              hipStream_t stream) {
  const float* tensor = (const float*)d_in[0];  // [256][1024]
  const float* z      = (const float*)d_in[1];  // [256][16]
  const float* W      = (const float*)d_in[2];  // [1024][1024]
  const float* bias   = (const float*)d_in[3];  // [1024]
  const float* lt_w   = (const float*)d_in[4];  // [1024][16]
  const float* lt_b   = (const float*)d_in[5];  // [1024]
  float* out = (float*)d_out;

  // workspace: xs[512K] ss[512K] wt[2M] w2t[2M]  (5 MB)
  char* ws = (char*)d_ws;
  __hip_bfloat16* xsb = (__hip_bfloat16*)(ws);
  __hip_bfloat16* ssb = (__hip_bfloat16*)(ws + 512 * 1024);
  __hip_bfloat16* wt  = (__hip_bfloat16*)(ws + 1024 * 1024);
  __hip_bfloat16* w2t = (__hip_bfloat16*)(ws + 3 * 1024 * 1024);

  prep<<<1024 + BATCH, 256, 0, stream>>>(tensor, z, lt_w, lt_b, W,
                                         xsb, ssb, wt, w2t);
  gemm_mod<<<dim3(OUT_F / 32, BATCH / 32), 256, 0, stream>>>(
      xsb, ssb, wt, w2t, bias, out);
}